// Round 4
// baseline (1795.154 us; speedup 1.0000x reference)
//
#include <hip/hip_runtime.h>

#define NB_ 16
#define TQ_ 2048
#define TS_ 2048
#define DH_ 1024
#define QB_ 32
#define SB_ 64
#define NT_ 512

typedef _Float16 f16x8 __attribute__((ext_vector_type(8)));
typedef _Float16 f16x4 __attribute__((ext_vector_type(4)));
typedef float f32x4 __attribute__((ext_vector_type(4)));

__global__ void convert_f32_f16(const float* __restrict__ src, _Float16* __restrict__ dst) {
  size_t i = ((size_t)blockIdx.x * blockDim.x + threadIdx.x) * 8;
  float4 v0 = *(const float4*)(src + i);
  float4 v1 = *(const float4*)(src + i + 4);
  f16x8 o;
  o[0] = (_Float16)v0.x; o[1] = (_Float16)v0.y; o[2] = (_Float16)v0.z; o[3] = (_Float16)v0.w;
  o[4] = (_Float16)v1.x; o[5] = (_Float16)v1.y; o[6] = (_Float16)v1.z; o[7] = (_Float16)v1.w;
  *(f16x8*)(dst + i) = o;
}

__device__ inline f16x8 cvt8(const float* __restrict__ fp) {
  float4 a = *(const float4*)fp;
  float4 b = *(const float4*)(fp + 4);
  f16x8 t;
  t[0] = (_Float16)a.x; t[1] = (_Float16)a.y; t[2] = (_Float16)a.z; t[3] = (_Float16)a.w;
  t[4] = (_Float16)b.x; t[5] = (_Float16)b.y; t[6] = (_Float16)b.z; t[7] = (_Float16)b.w;
  return t;
}

// MODE: 2 = enc+hid f16 in ws, 1 = enc f16 only, 0 = none
template<int MODE>
__device__ inline f16x8 ldE(const _Float16* __restrict__ hp, const float* __restrict__ fp, size_t idx) {
  if constexpr (MODE >= 1) return *(const f16x8*)(hp + idx);
  else return cvt8(fp + idx);
}
template<int MODE>
__device__ inline f16x8 ldQ(const _Float16* __restrict__ hp, const float* __restrict__ fp, size_t idx) {
  if constexpr (MODE == 2) return *(const f16x8*)(hp + idx);
  else return cvt8(fp + idx);
}

// LDS layout (bytes), total 72064 -> 2 WGs/CU:
//   vt     : 0     .. 32768   per-wave V-transpose buffers, 8 x 4096
//            wave w pass: Vt[64 h][32 s] f16, byte = (h*64+s*2) ^ (((h>>3)&7)<<4)
//   s_tiles: 32768 .. 67584   4 tiles [dw][32 q][68] f32
//   p_base : 67584 .. 71680   P [32 q][64 s] f16, byte = (q*128+s*2) ^ ((q&7)<<4)
//   m/l/c  : 71680 .. 72064   softmax state
template<int MODE>
__global__ __launch_bounds__(NT_, 4)
void attn_v4(const float* __restrict__ hid,
             const float* __restrict__ enc,
             const _Float16* __restrict__ encH,
             const _Float16* __restrict__ hidH,
             float* __restrict__ out) {
  __shared__ __attribute__((aligned(16))) char smem[72064];
  char*  const vt_all  = smem;
  float* const s_tiles = (float*)(smem + 32768);
  char*  const p_base  = smem + 67584;
  float* const m_lds   = (float*)(smem + 71680);
  float* const l_lds   = m_lds + 32;
  float* const c_lds   = m_lds + 64;

  const int tid  = threadIdx.x;
  const int lane = tid & 63;
  const int wid  = tid >> 6;
  const int arow = lane & 15;
  const int agrp = lane >> 4;

  // XCD-affine block mapping: XCD x serves batches 2x, 2x+1
  const int bi = blockIdx.x;
  const int x  = bi & 7;
  const int j  = bi >> 3;
  const int r_ = j >> 5;
  const int b  = x * 2 + (r_ >> 1);
  const int q0 = ((j & 31) + ((r_ & 1) << 5)) * QB_;

  const int dw = wid & 3;   // QK^T d-chunk (256 wide)
  const int sh = wid >> 2;  // QK^T s-half (32 wide)
  const int hw = wid;       // PV h-chunk (128 wide), rounds of 64

  if (tid < 32) { m_lds[tid] = -__builtin_inff(); l_lds[tid] = 0.0f; }

  f32x4 o_acc[2][2][4];   // [h-round][m][n]
  #pragma unroll
  for (int r = 0; r < 2; ++r)
    #pragma unroll
    for (int m = 0; m < 2; ++m)
      #pragma unroll
      for (int n = 0; n < 4; ++n)
        o_acc[r][m][n] = {};

  char* const vt = vt_all + wid * 4096;
  const size_t enc_b = (size_t)b * TS_ * DH_;
  const size_t hid_b = (size_t)(b * TQ_ + q0) * DH_;
  const int c8 = (lane & 7) * 8;        // V staging h-octet (within 64)
  const int d2 = (lane >> 3) * 2;       // V staging s-pair base

  for (int st = 0; st < TS_ / SB_; ++st) {
    const int s0 = st * SB_;

    // ================= QK^T: stream Q and K frags from global =================
    f32x4 sacc[2][2] = {{{}, {}}, {{}, {}}};
    #pragma unroll
    for (int kf = 0; kf < 8; ++kf) {
      const int doff = dw * 256 + kf * 32 + agrp * 8;
      f16x8 aq0 = ldQ<MODE>(hidH, hid, hid_b + (size_t)(arow) * DH_ + doff);
      f16x8 aq1 = ldQ<MODE>(hidH, hid, hid_b + (size_t)(16 + arow) * DH_ + doff);
      size_t kb = enc_b + (size_t)(s0 + sh * 32 + arow) * DH_ + doff;
      f16x8 bf0 = ldE<MODE>(encH, enc, kb);
      f16x8 bf1 = ldE<MODE>(encH, enc, kb + (size_t)16 * DH_);
      sacc[0][0] = __builtin_amdgcn_mfma_f32_16x16x32_f16(aq0, bf0, sacc[0][0], 0, 0, 0);
      sacc[0][1] = __builtin_amdgcn_mfma_f32_16x16x32_f16(aq0, bf1, sacc[0][1], 0, 0, 0);
      sacc[1][0] = __builtin_amdgcn_mfma_f32_16x16x32_f16(aq1, bf0, sacc[1][0], 0, 0, 0);
      sacc[1][1] = __builtin_amdgcn_mfma_f32_16x16x32_f16(aq1, bf1, sacc[1][1], 0, 0, 0);
    }

    // write partial S tile [dw][32 q][68]
    {
      float* tp = s_tiles + (size_t)dw * (32 * 68);
      #pragma unroll
      for (int m = 0; m < 2; ++m)
        #pragma unroll
        for (int n = 0; n < 2; ++n)
          #pragma unroll
          for (int i2 = 0; i2 < 4; ++i2)
            tp[(m * 16 + agrp * 4 + i2) * 68 + sh * 32 + n * 16 + arow] = sacc[m][n][i2];
    }

    __syncthreads();  // b1: S complete

    // ================= online softmax =================
    {
      int q = tid >> 4, sq = tid & 15;
      const float* bp = s_tiles + q * 68 + sq * 4;
      f32x4 v = *(const f32x4*)bp;
      v += *(const f32x4*)(bp + 2176);
      v += *(const f32x4*)(bp + 4352);
      v += *(const f32x4*)(bp + 6528);
      float mx = fmaxf(fmaxf(v[0], v[1]), fmaxf(v[2], v[3]));
      #pragma unroll
      for (int o = 8; o; o >>= 1) mx = fmaxf(mx, __shfl_xor(mx, o));
      float mprev = m_lds[q];
      float mnew  = fmaxf(mprev, mx);
      float p0 = __expf(v[0] - mnew), p1 = __expf(v[1] - mnew);
      float p2 = __expf(v[2] - mnew), p3 = __expf(v[3] - mnew);
      float ps = (p0 + p1) + (p2 + p3);
      #pragma unroll
      for (int o = 8; o; o >>= 1) ps += __shfl_xor(ps, o);
      if (sq == 0) {
        float cf = __expf(mprev - mnew);
        m_lds[q] = mnew;
        l_lds[q] = l_lds[q] * cf + ps;
        c_lds[q] = cf;
      }
      f16x4 pw;
      pw[0] = (_Float16)p0; pw[1] = (_Float16)p1;
      pw[2] = (_Float16)p2; pw[3] = (_Float16)p3;
      *(f16x4*)(p_base + ((q * 128 + sq * 8) ^ ((q & 7) << 4))) = pw;
    }

    __syncthreads();  // b2: P + m/l/c complete

    // ---- rescale O ----
    #pragma unroll
    for (int m = 0; m < 2; ++m)
      #pragma unroll
      for (int i2 = 0; i2 < 4; ++i2) {
        float cf = c_lds[m * 16 + agrp * 4 + i2];
        #pragma unroll
        for (int r = 0; r < 2; ++r)
          #pragma unroll
          for (int n = 0; n < 4; ++n)
            o_acc[r][m][n][i2] *= cf;
      }

    // ================= PV: 4 passes (h-round r = pass>>1, s-phase = pass&1) =================
    f16x8 stg[2][2][2];  // [buf][it][row-in-pair]
    {
      // load pass 0: r=0, sphase=0
      #pragma unroll
      for (int it = 0; it < 2; ++it) {
        size_t base = enc_b + (size_t)(s0 + it * 16 + d2) * DH_ + hw * 128 + c8;
        stg[0][it][0] = ldE<MODE>(encH, enc, base);
        stg[0][it][1] = ldE<MODE>(encH, enc, base + DH_);
      }
    }
    #pragma unroll
    for (int pass = 0; pass < 4; ++pass) {
      const int r = pass >> 1, sphase = pass & 1;
      if (pass < 3) {
        const int rn = (pass + 1) >> 1, spn = (pass + 1) & 1;
        #pragma unroll
        for (int it = 0; it < 2; ++it) {
          size_t base = enc_b + (size_t)(s0 + spn * 32 + it * 16 + d2) * DH_
                        + hw * 128 + rn * 64 + c8;
          stg[(pass + 1) & 1][it][0] = ldE<MODE>(encH, enc, base);
          stg[(pass + 1) & 1][it][1] = ldE<MODE>(encH, enc, base + DH_);
        }
      }
      // write Vt (wave-private, DS in-order)
      #pragma unroll
      for (int it = 0; it < 2; ++it) {
        int sl = it * 16 + d2;
        #pragma unroll
        for (int jj = 0; jj < 8; ++jj) {
          int hl = c8 + jj;
          union { _Float16 h[2]; uint32_t u; } pk;
          pk.h[0] = stg[pass & 1][it][0][jj];
          pk.h[1] = stg[pass & 1][it][1][jj];
          *(uint32_t*)(vt + ((hl * 64 + sl * 2) ^ (((hl >> 3) & 7) << 4))) = pk.u;
        }
      }
      // P frags for this s-phase
      f16x8 pa0 = *(const f16x8*)(p_base +
          (((arow) * 128 + sphase * 64 + agrp * 16) ^ ((arow & 7) << 4)));
      f16x8 pa1 = *(const f16x8*)(p_base +
          (((16 + arow) * 128 + sphase * 64 + agrp * 16) ^ ((arow & 7) << 4)));
      __builtin_amdgcn_s_setprio(1);
      #pragma unroll
      for (int n = 0; n < 4; ++n) {
        int hl = n * 16 + arow;
        f16x8 bv = *(const f16x8*)(vt + ((hl * 64 + agrp * 16) ^ (((hl >> 3) & 7) << 4)));
        o_acc[r][0][n] = __builtin_amdgcn_mfma_f32_16x16x32_f16(pa0, bv, o_acc[r][0][n], 0, 0, 0);
        o_acc[r][1][n] = __builtin_amdgcn_mfma_f32_16x16x32_f16(pa1, bv, o_acc[r][1][n], 0, 0, 0);
      }
      __builtin_amdgcn_s_setprio(0);
    }
  }

  // ================= epilogue: O / l =================
  #pragma unroll
  for (int m = 0; m < 2; ++m) {
    #pragma unroll
    for (int i2 = 0; i2 < 4; ++i2) {
      int qr = m * 16 + agrp * 4 + i2;
      float inv = 1.0f / l_lds[qr];
      #pragma unroll
      for (int r = 0; r < 2; ++r)
        #pragma unroll
        for (int n = 0; n < 4; ++n)
          out[((size_t)(b * TQ_ + q0 + qr)) * DH_ + hw * 128 + r * 64 + n * 16 + arow] =
              o_acc[r][m][n][i2] * inv;
    }
  }
}

extern "C" void kernel_launch(void* const* d_in, const int* in_sizes, int n_in,
                              void* d_out, int out_size, void* d_ws, size_t ws_size,
                              hipStream_t stream) {
  (void)in_sizes; (void)n_in; (void)out_size;
  const float* hid = (const float*)d_in[0];
  const float* enc = (const float*)d_in[1];
  float* out = (float*)d_out;

  const size_t N = (size_t)NB_ * TS_ * DH_;  // 33554432 elements (enc == hid size)
  const int mode = (ws_size >= 2 * N * sizeof(_Float16)) ? 2
                 : (ws_size >= N * sizeof(_Float16)) ? 1 : 0;

  dim3 grid(NB_ * (TQ_ / QB_), 1, 1);
  dim3 block(NT_, 1, 1);
  dim3 cgrid((unsigned)(N / 8 / 256)), cblock(256);

  if (mode == 2) {
    _Float16* encH = (_Float16*)d_ws;
    _Float16* hidH = encH + N;
    convert_f32_f16<<<cgrid, cblock, 0, stream>>>(enc, encH);
    convert_f32_f16<<<cgrid, cblock, 0, stream>>>(hid, hidH);
    attn_v4<2><<<grid, block, 0, stream>>>(hid, enc, encH, hidH, out);
  } else if (mode == 1) {
    _Float16* encH = (_Float16*)d_ws;
    convert_f32_f16<<<cgrid, cblock, 0, stream>>>(enc, encH);
    attn_v4<1><<<grid, block, 0, stream>>>(hid, enc, encH, nullptr, out);
  } else {
    attn_v4<0><<<grid, block, 0, stream>>>(hid, enc, nullptr, nullptr, out);
  }
}

// Round 5
// 1745.454 us; speedup vs baseline: 1.0285x; 1.0285x over previous
//
#include <hip/hip_runtime.h>

#define NB_ 16
#define TQ_ 2048
#define TS_ 2048
#define DH_ 1024
#define QB_ 32
#define SB_ 64
#define NT_ 512

typedef _Float16 f16x8 __attribute__((ext_vector_type(8)));
typedef _Float16 f16x4 __attribute__((ext_vector_type(4)));
typedef float f32x4 __attribute__((ext_vector_type(4)));

__global__ void convert_f32_f16(const float* __restrict__ src, _Float16* __restrict__ dst) {
  size_t i = ((size_t)blockIdx.x * blockDim.x + threadIdx.x) * 8;
  float4 v0 = *(const float4*)(src + i);
  float4 v1 = *(const float4*)(src + i + 4);
  f16x8 o;
  o[0] = (_Float16)v0.x; o[1] = (_Float16)v0.y; o[2] = (_Float16)v0.z; o[3] = (_Float16)v0.w;
  o[4] = (_Float16)v1.x; o[5] = (_Float16)v1.y; o[6] = (_Float16)v1.z; o[7] = (_Float16)v1.w;
  *(f16x8*)(dst + i) = o;
}

template<bool WS16>
__device__ inline f16x8 ld8(const _Float16* __restrict__ hp, const float* __restrict__ fp, size_t idx) {
  if constexpr (WS16) {
    return *(const f16x8*)(hp + idx);
  } else {
    float4 a = *(const float4*)(fp + idx);
    float4 b = *(const float4*)(fp + idx + 4);
    f16x8 t;
    t[0] = (_Float16)a.x; t[1] = (_Float16)a.y; t[2] = (_Float16)a.z; t[3] = (_Float16)a.w;
    t[4] = (_Float16)b.x; t[5] = (_Float16)b.y; t[6] = (_Float16)b.z; t[7] = (_Float16)b.w;
    return t;
  }
}

// LDS layout identical to v2 (passed correctness):
//   vt     : 0      .. 65536   per-wave private V-transpose buffers, 8 x 8192
//            wave w: Vt[128 h][32 s] f16, byte = (h*64 + s*2) ^ (((h>>3)&7)<<4)
//   s_tiles: 65536  .. 102400  8 tiles [(sh*4+dw)][32 q][36] f32
//   p_base : 102400 .. 106496  P [32 q][64 s] f16, byte = (q*128 + s*2) ^ ((q&7)<<4)
//   m/l/c  : 106496 .. 106880  softmax state
template<bool WS16>
__global__ __launch_bounds__(NT_)   // single-arg: allow up to 256 VGPR, 1 WG/CU (LDS-capped anyway)
void attn_v5(const float* __restrict__ hid,
             const float* __restrict__ enc,
             const _Float16* __restrict__ encH,
             float* __restrict__ out) {
  __shared__ __attribute__((aligned(16))) char smem[106880];
  char*  const vt_all  = smem;
  float* const s_tiles = (float*)(smem + 65536);
  char*  const p_base  = smem + 102400;
  float* const m_lds   = (float*)(smem + 106496);
  float* const l_lds   = m_lds + 32;
  float* const c_lds   = m_lds + 64;

  const int tid  = threadIdx.x;
  const int lane = tid & 63;
  const int wid  = tid >> 6;
  const int arow = lane & 15;
  const int agrp = lane >> 4;

  // XCD-affine block mapping: XCD x sweeps batch 2x fully (32+32 q-tiles), then 2x+1.
  // Resident set per XCD = one batch's enc slab (4 MB f16) -> L2-resident, lockstep sweep.
  const int bi = blockIdx.x;
  const int x  = bi & 7;
  const int j  = bi >> 3;
  const int r  = j >> 5;
  const int b  = x * 2 + (r >> 1);
  const int q0 = ((j & 31) + ((r & 1) << 5)) * QB_;

  const int dw = wid & 3;   // QK^T d-chunk (256 wide)
  const int sh = wid >> 2;  // QK^T s-half (32 wide)
  const int hw = wid;       // PV h-chunk (128 wide)

  if (tid < 32) { m_lds[tid] = -__builtin_inff(); l_lds[tid] = 0.0f; }

  // ---- Q fragments in registers (persistent, 64 VGPR) ----
  f16x8 a_q[2][8];
  #pragma unroll
  for (int m = 0; m < 2; ++m) {
    #pragma unroll
    for (int kf = 0; kf < 8; ++kf) {
      const float* qp = hid + ((size_t)(b * TQ_ + q0 + m * 16 + arow)) * DH_
                            + dw * 256 + kf * 32 + agrp * 8;
      float4 v0 = *(const float4*)qp;
      float4 v1 = *(const float4*)(qp + 4);
      f16x8 t;
      t[0] = (_Float16)v0.x; t[1] = (_Float16)v0.y; t[2] = (_Float16)v0.z; t[3] = (_Float16)v0.w;
      t[4] = (_Float16)v1.x; t[5] = (_Float16)v1.y; t[6] = (_Float16)v1.z; t[7] = (_Float16)v1.w;
      a_q[m][kf] = t;
    }
  }

  f32x4 o_acc[2][8];   // 64 VGPR persistent
  #pragma unroll
  for (int m = 0; m < 2; ++m)
    #pragma unroll
    for (int n = 0; n < 8; ++n)
      o_acc[m][n] = {};

  char* const vt = vt_all + wid * 8192;
  const size_t enc_b = (size_t)b * TS_ * DH_;
  const int h8 = (lane & 15) * 8;
  const int spb = (lane >> 4) * 2;

  // Cross-tile prefetch: first half of K (32 VGPR)
  f16x8 kpre[2][4];
  auto preK = [&](int s0) {
    #pragma unroll
    for (int kf = 0; kf < 4; ++kf) {
      size_t kb = enc_b + (size_t)(s0 + sh * 32 + arow) * DH_ + dw * 256 + kf * 32 + agrp * 8;
      kpre[0][kf] = ld8<WS16>(encH, enc, kb);
      kpre[1][kf] = ld8<WS16>(encH, enc, kb + (size_t)16 * DH_);
    }
  };

  preK(0);

  for (int st = 0; st < TS_ / SB_; ++st) {
    const int s0 = st * SB_;

    // ---- QK^T: issue second-half K loads, MFMA on kpre (resident), then krest ----
    f16x8 krest[2][4];
    #pragma unroll
    for (int kf = 0; kf < 4; ++kf) {
      size_t kb = enc_b + (size_t)(s0 + sh * 32 + arow) * DH_ + dw * 256 + (kf + 4) * 32 + agrp * 8;
      krest[0][kf] = ld8<WS16>(encH, enc, kb);
      krest[1][kf] = ld8<WS16>(encH, enc, kb + (size_t)16 * DH_);
    }

    f32x4 sacc[2][2] = {{{}, {}}, {{}, {}}};
    __builtin_amdgcn_s_setprio(1);
    #pragma unroll
    for (int kf = 0; kf < 4; ++kf) {
      sacc[0][0] = __builtin_amdgcn_mfma_f32_16x16x32_f16(a_q[0][kf], kpre[0][kf], sacc[0][0], 0, 0, 0);
      sacc[0][1] = __builtin_amdgcn_mfma_f32_16x16x32_f16(a_q[0][kf], kpre[1][kf], sacc[0][1], 0, 0, 0);
      sacc[1][0] = __builtin_amdgcn_mfma_f32_16x16x32_f16(a_q[1][kf], kpre[0][kf], sacc[1][0], 0, 0, 0);
      sacc[1][1] = __builtin_amdgcn_mfma_f32_16x16x32_f16(a_q[1][kf], kpre[1][kf], sacc[1][1], 0, 0, 0);
    }
    #pragma unroll
    for (int kf = 0; kf < 4; ++kf) {
      sacc[0][0] = __builtin_amdgcn_mfma_f32_16x16x32_f16(a_q[0][kf + 4], krest[0][kf], sacc[0][0], 0, 0, 0);
      sacc[0][1] = __builtin_amdgcn_mfma_f32_16x16x32_f16(a_q[0][kf + 4], krest[1][kf], sacc[0][1], 0, 0, 0);
      sacc[1][0] = __builtin_amdgcn_mfma_f32_16x16x32_f16(a_q[1][kf + 4], krest[0][kf], sacc[1][0], 0, 0, 0);
      sacc[1][1] = __builtin_amdgcn_mfma_f32_16x16x32_f16(a_q[1][kf + 4], krest[1][kf], sacc[1][1], 0, 0, 0);
    }
    __builtin_amdgcn_s_setprio(0);

    // ---- issue PV phase-0 V loads (arrive during S-write + softmax + barriers) ----
    f16x8 stA[4][2];
    #pragma unroll
    for (int it = 0; it < 4; ++it) {
      size_t base = enc_b + (size_t)(s0 + it * 8 + spb) * DH_ + hw * 128 + h8;
      stA[it][0] = ld8<WS16>(encH, enc, base);
      stA[it][1] = ld8<WS16>(encH, enc, base + DH_);
    }

    // write partial S tile (sh*4+dw): [32 q][36] f32
    {
      float* tp = s_tiles + (size_t)(sh * 4 + dw) * (32 * 36);
      #pragma unroll
      for (int m = 0; m < 2; ++m)
        #pragma unroll
        for (int n = 0; n < 2; ++n)
          #pragma unroll
          for (int i2 = 0; i2 < 4; ++i2)
            tp[(m * 16 + agrp * 4 + i2) * 36 + n * 16 + arow] = sacc[m][n][i2];
    }

    __syncthreads();  // b1: S complete

    // ---- online softmax ----
    {
      int q = tid >> 4, sq = tid & 15;
      int shh = sq >> 3, sc = (sq & 7) * 4;
      const float* basep = s_tiles + (size_t)shh * 4 * (32 * 36) + q * 36 + sc;
      f32x4 v = *(const f32x4*)basep;
      v += *(const f32x4*)(basep + 1152);
      v += *(const f32x4*)(basep + 2304);
      v += *(const f32x4*)(basep + 3456);
      float mx = fmaxf(fmaxf(v[0], v[1]), fmaxf(v[2], v[3]));
      #pragma unroll
      for (int o = 8; o; o >>= 1) mx = fmaxf(mx, __shfl_xor(mx, o));
      float mprev = m_lds[q];
      float mnew  = fmaxf(mprev, mx);
      float p0 = __expf(v[0] - mnew), p1 = __expf(v[1] - mnew);
      float p2 = __expf(v[2] - mnew), p3 = __expf(v[3] - mnew);
      float ps = (p0 + p1) + (p2 + p3);
      #pragma unroll
      for (int o = 8; o; o >>= 1) ps += __shfl_xor(ps, o);
      if (sq == 0) {
        float cf = __expf(mprev - mnew);
        m_lds[q] = mnew;
        l_lds[q] = l_lds[q] * cf + ps;
        c_lds[q] = cf;
      }
      f16x4 pw;
      pw[0] = (_Float16)p0; pw[1] = (_Float16)p1;
      pw[2] = (_Float16)p2; pw[3] = (_Float16)p3;
      *(f16x4*)(p_base + ((q * 128 + sq * 8) ^ ((q & 7) << 4))) = pw;
    }

    __syncthreads();  // b2: P + m/l/c complete

    // ---- rescale O ----
    #pragma unroll
    for (int m = 0; m < 2; ++m)
      #pragma unroll
      for (int i2 = 0; i2 < 4; ++i2) {
        float cf = c_lds[m * 16 + agrp * 4 + i2];
        #pragma unroll
        for (int n = 0; n < 8; ++n) o_acc[m][n][i2] *= cf;
      }

    // ---- PV phase 0: issue stB loads, hoist P reads, write Vt from stA, MFMA ----
    f16x8 stB[4][2];
    #pragma unroll
    for (int it = 0; it < 4; ++it) {
      size_t base = enc_b + (size_t)(s0 + 32 + it * 8 + spb) * DH_ + hw * 128 + h8;
      stB[it][0] = ld8<WS16>(encH, enc, base);
      stB[it][1] = ld8<WS16>(encH, enc, base + DH_);
    }
    f16x8 pa0  = *(const f16x8*)(p_base + (((arow) * 128 + agrp * 16) ^ ((arow & 7) << 4)));
    f16x8 pa1  = *(const f16x8*)(p_base + (((16 + arow) * 128 + agrp * 16) ^ ((arow & 7) << 4)));
    f16x8 pa0b = *(const f16x8*)(p_base + (((arow) * 128 + 64 + agrp * 16) ^ ((arow & 7) << 4)));
    f16x8 pa1b = *(const f16x8*)(p_base + (((16 + arow) * 128 + 64 + agrp * 16) ^ ((arow & 7) << 4)));

    #pragma unroll
    for (int it = 0; it < 4; ++it) {
      int sp = it * 8 + spb;
      #pragma unroll
      for (int jj = 0; jj < 8; ++jj) {
        int hloc = h8 + jj;
        union { _Float16 h[2]; uint32_t u; } pk;
        pk.h[0] = stA[it][0][jj]; pk.h[1] = stA[it][1][jj];
        *(uint32_t*)(vt + ((hloc * 64 + sp * 2) ^ (((hloc >> 3) & 7) << 4))) = pk.u;
      }
    }
    __builtin_amdgcn_s_setprio(1);
    #pragma unroll
    for (int n = 0; n < 8; ++n) {
      int hloc = n * 16 + arow;
      f16x8 bv = *(const f16x8*)(vt + ((hloc * 64 + agrp * 16) ^ (((hloc >> 3) & 7) << 4)));
      o_acc[0][n] = __builtin_amdgcn_mfma_f32_16x16x32_f16(pa0, bv, o_acc[0][n], 0, 0, 0);
      o_acc[1][n] = __builtin_amdgcn_mfma_f32_16x16x32_f16(pa1, bv, o_acc[1][n], 0, 0, 0);
    }
    __builtin_amdgcn_s_setprio(0);

    // ---- PV phase 1: prefetch next tile's K first-half, write Vt from stB, MFMA ----
    if (st + 1 < TS_ / SB_) preK(s0 + SB_);
    #pragma unroll
    for (int it = 0; it < 4; ++it) {
      int sp = it * 8 + spb;
      #pragma unroll
      for (int jj = 0; jj < 8; ++jj) {
        int hloc = h8 + jj;
        union { _Float16 h[2]; uint32_t u; } pk;
        pk.h[0] = stB[it][0][jj]; pk.h[1] = stB[it][1][jj];
        *(uint32_t*)(vt + ((hloc * 64 + sp * 2) ^ (((hloc >> 3) & 7) << 4))) = pk.u;
      }
    }
    __builtin_amdgcn_s_setprio(1);
    #pragma unroll
    for (int n = 0; n < 8; ++n) {
      int hloc = n * 16 + arow;
      f16x8 bv = *(const f16x8*)(vt + ((hloc * 64 + agrp * 16) ^ (((hloc >> 3) & 7) << 4)));
      o_acc[0][n] = __builtin_amdgcn_mfma_f32_16x16x32_f16(pa0b, bv, o_acc[0][n], 0, 0, 0);
      o_acc[1][n] = __builtin_amdgcn_mfma_f32_16x16x32_f16(pa1b, bv, o_acc[1][n], 0, 0, 0);
    }
    __builtin_amdgcn_s_setprio(0);
  }

  // ---- epilogue: O / l ----
  #pragma unroll
  for (int m = 0; m < 2; ++m) {
    #pragma unroll
    for (int i2 = 0; i2 < 4; ++i2) {
      int qr = m * 16 + agrp * 4 + i2;
      float inv = 1.0f / l_lds[qr];
      #pragma unroll
      for (int n = 0; n < 8; ++n) {
        out[((size_t)(b * TQ_ + q0 + qr)) * DH_ + hw * 128 + n * 16 + arow] =
            o_acc[m][n][i2] * inv;
      }
    }
  }
}

extern "C" void kernel_launch(void* const* d_in, const int* in_sizes, int n_in,
                              void* d_out, int out_size, void* d_ws, size_t ws_size,
                              hipStream_t stream) {
  (void)in_sizes; (void)n_in; (void)out_size;
  const float* hid = (const float*)d_in[0];
  const float* enc = (const float*)d_in[1];
  float* out = (float*)d_out;

  const size_t encN = (size_t)NB_ * TS_ * DH_;
  const bool ws16 = (ws_size >= encN * sizeof(_Float16));

  dim3 grid(NB_ * (TQ_ / QB_), 1, 1);
  dim3 block(NT_, 1, 1);

  if (ws16) {
    _Float16* encH = (_Float16*)d_ws;
    convert_f32_f16<<<dim3((unsigned)(encN / 8 / 256)), dim3(256), 0, stream>>>(enc, encH);
    attn_v5<true><<<grid, block, 0, stream>>>(hid, enc, encH, out);
  } else {
    attn_v5<false><<<grid, block, 0, stream>>>(hid, enc, nullptr, out);
  }
}

// Round 6
// 1715.120 us; speedup vs baseline: 1.0467x; 1.0177x over previous
//
#include <hip/hip_runtime.h>

#define NB_ 16
#define TQ_ 2048
#define TS_ 2048
#define DH_ 1024
#define QB_ 32
#define SB_ 64
#define NT_ 512

typedef _Float16 f16x8 __attribute__((ext_vector_type(8)));
typedef _Float16 f16x4 __attribute__((ext_vector_type(4)));
typedef float f32x4 __attribute__((ext_vector_type(4)));

__global__ void convert_f32_f16(const float* __restrict__ src, _Float16* __restrict__ dst) {
  size_t i = ((size_t)blockIdx.x * blockDim.x + threadIdx.x) * 8;
  float4 v0 = *(const float4*)(src + i);
  float4 v1 = *(const float4*)(src + i + 4);
  f16x8 o;
  o[0] = (_Float16)v0.x; o[1] = (_Float16)v0.y; o[2] = (_Float16)v0.z; o[3] = (_Float16)v0.w;
  o[4] = (_Float16)v1.x; o[5] = (_Float16)v1.y; o[6] = (_Float16)v1.z; o[7] = (_Float16)v1.w;
  *(f16x8*)(dst + i) = o;
}

template<bool WS16>
__device__ inline f16x8 ld8(const _Float16* __restrict__ hp, const float* __restrict__ fp, size_t idx) {
  if constexpr (WS16) {
    return *(const f16x8*)(hp + idx);
  } else {
    float4 a = *(const float4*)(fp + idx);
    float4 b = *(const float4*)(fp + idx + 4);
    f16x8 t;
    t[0] = (_Float16)a.x; t[1] = (_Float16)a.y; t[2] = (_Float16)a.z; t[3] = (_Float16)a.w;
    t[4] = (_Float16)b.x; t[5] = (_Float16)b.y; t[6] = (_Float16)b.z; t[7] = (_Float16)b.w;
    return t;
  }
}

// LDS layout (bytes), total 74112 -> 2 WGs/CU (16 waves/CU):
//   vt     : 0     .. 32768   per-wave V-transpose buffers, 8 x 4096
//            per pass: Vt[64 h][32 s] f16, byte = (h*64+s*2) ^ (((h>>3)&7)<<4)
//   s_tiles: 32768 .. 69632   8 tiles [(sh*4+dw)][32 q][36] f32
//   p_base : 69632 .. 73728   P [32 q][64 s] f16, byte = (q*128+s*2) ^ ((q&7)<<4)
//   m/l/c  : 73728 .. 74112   softmax state
template<bool WS16>
__global__ __launch_bounds__(NT_, 4)   // cap 128 VGPR -> 2 WGs/CU with 74KB LDS
void attn_v6(const float* __restrict__ hid,
             const float* __restrict__ enc,
             const _Float16* __restrict__ encH,
             float* __restrict__ out) {
  __shared__ __attribute__((aligned(16))) char smem[74112];
  char*  const vt_all  = smem;
  float* const s_tiles = (float*)(smem + 32768);
  char*  const p_base  = smem + 69632;
  float* const m_lds   = (float*)(smem + 73728);
  float* const l_lds   = m_lds + 32;
  float* const c_lds   = m_lds + 64;

  const int tid  = threadIdx.x;
  const int lane = tid & 63;
  const int wid  = tid >> 6;
  const int arow = lane & 15;
  const int agrp = lane >> 4;

  // XCD-affine: XCD x sweeps ALL 64 q-tiles of batch x (round 0), then batch x+8.
  // 64 resident WGs/XCD (2 WGs/CU x 32 CUs) = one batch -> enc slab 4 MB f16 = L2-exact.
  const int bi  = blockIdx.x;
  const int x   = bi & 7;
  const int idx = bi >> 3;            // 0..127
  const int b   = x + 8 * (idx >> 6);
  const int q0  = (idx & 63) * QB_;

  const int dw = wid & 3;   // QK^T d-chunk (256 wide)
  const int sh = wid >> 2;  // QK^T s-half (32 wide)
  const int hw = wid;       // PV h-chunk (128 wide), 2 rounds of 64

  if (tid < 32) { m_lds[tid] = -__builtin_inff(); l_lds[tid] = 0.0f; }

  // ---- Q fragments in registers (persistent, 64 VGPR) ----
  f16x8 a_q[2][8];
  #pragma unroll
  for (int m = 0; m < 2; ++m) {
    #pragma unroll
    for (int kf = 0; kf < 8; ++kf) {
      const float* qp = hid + ((size_t)(b * TQ_ + q0 + m * 16 + arow)) * DH_
                            + dw * 256 + kf * 32 + agrp * 8;
      float4 v0 = *(const float4*)qp;
      float4 v1 = *(const float4*)(qp + 4);
      f16x8 t;
      t[0] = (_Float16)v0.x; t[1] = (_Float16)v0.y; t[2] = (_Float16)v0.z; t[3] = (_Float16)v0.w;
      t[4] = (_Float16)v1.x; t[5] = (_Float16)v1.y; t[6] = (_Float16)v1.z; t[7] = (_Float16)v1.w;
      a_q[m][kf] = t;
    }
  }

  f32x4 o_acc[2][2][4];   // [h-round][m][n] = 64 VGPR persistent
  #pragma unroll
  for (int r = 0; r < 2; ++r)
    #pragma unroll
    for (int m = 0; m < 2; ++m)
      #pragma unroll
      for (int n = 0; n < 4; ++n)
        o_acc[r][m][n] = {};

  char* const vt = vt_all + wid * 4096;
  const size_t enc_b = (size_t)b * TS_ * DH_;
  const int c8 = (lane & 7) * 8;        // V staging h-octet (within 64)
  const int d2 = (lane >> 3) * 2;       // V staging s-pair base

  for (int st = 0; st < TS_ / SB_; ++st) {
    const int s0 = st * SB_;

    // ================= QK^T: K frags inline from global (L2-hot) =================
    f32x4 sacc[2][2] = {{{}, {}}, {{}, {}}};
    #pragma unroll
    for (int kf = 0; kf < 8; ++kf) {
      size_t kb = enc_b + (size_t)(s0 + sh * 32 + arow) * DH_ + dw * 256 + kf * 32 + agrp * 8;
      f16x8 bf0 = ld8<WS16>(encH, enc, kb);
      f16x8 bf1 = ld8<WS16>(encH, enc, kb + (size_t)16 * DH_);
      sacc[0][0] = __builtin_amdgcn_mfma_f32_16x16x32_f16(a_q[0][kf], bf0, sacc[0][0], 0, 0, 0);
      sacc[0][1] = __builtin_amdgcn_mfma_f32_16x16x32_f16(a_q[0][kf], bf1, sacc[0][1], 0, 0, 0);
      sacc[1][0] = __builtin_amdgcn_mfma_f32_16x16x32_f16(a_q[1][kf], bf0, sacc[1][0], 0, 0, 0);
      sacc[1][1] = __builtin_amdgcn_mfma_f32_16x16x32_f16(a_q[1][kf], bf1, sacc[1][1], 0, 0, 0);
    }

    // ---- issue PV pass-0 V loads (arrive during S-write + softmax + barriers) ----
    f16x8 stg[2][2][2];  // [buf][it][row-in-pair]
    #pragma unroll
    for (int it = 0; it < 2; ++it) {
      size_t base = enc_b + (size_t)(s0 + it * 16 + d2) * DH_ + hw * 128 + c8;
      stg[0][it][0] = ld8<WS16>(encH, enc, base);
      stg[0][it][1] = ld8<WS16>(encH, enc, base + DH_);
    }

    // write partial S tile (sh*4+dw): [32 q][36] f32
    {
      float* tp = s_tiles + (size_t)(sh * 4 + dw) * (32 * 36);
      #pragma unroll
      for (int m = 0; m < 2; ++m)
        #pragma unroll
        for (int n = 0; n < 2; ++n)
          #pragma unroll
          for (int i2 = 0; i2 < 4; ++i2)
            tp[(m * 16 + agrp * 4 + i2) * 36 + n * 16 + arow] = sacc[m][n][i2];
    }

    __syncthreads();  // b1: S complete

    // ---- online softmax ----
    {
      int q = tid >> 4, sq = tid & 15;
      int shh = sq >> 3, sc = (sq & 7) * 4;
      const float* basep = s_tiles + (size_t)shh * 4 * (32 * 36) + q * 36 + sc;
      f32x4 v = *(const f32x4*)basep;
      v += *(const f32x4*)(basep + 1152);
      v += *(const f32x4*)(basep + 2304);
      v += *(const f32x4*)(basep + 3456);
      float mx = fmaxf(fmaxf(v[0], v[1]), fmaxf(v[2], v[3]));
      #pragma unroll
      for (int o = 8; o; o >>= 1) mx = fmaxf(mx, __shfl_xor(mx, o));
      float mprev = m_lds[q];
      float mnew  = fmaxf(mprev, mx);
      float p0 = __expf(v[0] - mnew), p1 = __expf(v[1] - mnew);
      float p2 = __expf(v[2] - mnew), p3 = __expf(v[3] - mnew);
      float ps = (p0 + p1) + (p2 + p3);
      #pragma unroll
      for (int o = 8; o; o >>= 1) ps += __shfl_xor(ps, o);
      if (sq == 0) {
        float cf = __expf(mprev - mnew);
        m_lds[q] = mnew;
        l_lds[q] = l_lds[q] * cf + ps;
        c_lds[q] = cf;
      }
      f16x4 pw;
      pw[0] = (_Float16)p0; pw[1] = (_Float16)p1;
      pw[2] = (_Float16)p2; pw[3] = (_Float16)p3;
      *(f16x4*)(p_base + ((q * 128 + sq * 8) ^ ((q & 7) << 4))) = pw;
    }

    __syncthreads();  // b2: P + m/l/c complete

    // ---- rescale O ----
    #pragma unroll
    for (int m = 0; m < 2; ++m)
      #pragma unroll
      for (int i2 = 0; i2 < 4; ++i2) {
        float cf = c_lds[m * 16 + agrp * 4 + i2];
        #pragma unroll
        for (int r = 0; r < 2; ++r)
          #pragma unroll
          for (int n = 0; n < 4; ++n)
            o_acc[r][m][n][i2] *= cf;
      }

    // ================= PV: 4 passes (h-round r = pass>>1, s-phase = pass&1) =================
    #pragma unroll
    for (int pass = 0; pass < 4; ++pass) {
      const int r = pass >> 1, sphase = pass & 1;
      // prefetch next pass's V frags (hides under Vt write + MFMA)
      if (pass < 3) {
        const int rn = (pass + 1) >> 1, spn = (pass + 1) & 1;
        #pragma unroll
        for (int it = 0; it < 2; ++it) {
          size_t base = enc_b + (size_t)(s0 + spn * 32 + it * 16 + d2) * DH_
                        + hw * 128 + rn * 64 + c8;
          stg[(pass + 1) & 1][it][0] = ld8<WS16>(encH, enc, base);
          stg[(pass + 1) & 1][it][1] = ld8<WS16>(encH, enc, base + DH_);
        }
      }
      // write Vt (wave-private, DS in-order, no barrier)
      #pragma unroll
      for (int it = 0; it < 2; ++it) {
        int sl = it * 16 + d2;
        #pragma unroll
        for (int jj = 0; jj < 8; ++jj) {
          int hl = c8 + jj;
          union { _Float16 h[2]; uint32_t u; } pk;
          pk.h[0] = stg[pass & 1][it][0][jj];
          pk.h[1] = stg[pass & 1][it][1][jj];
          *(uint32_t*)(vt + ((hl * 64 + sl * 2) ^ (((hl >> 3) & 7) << 4))) = pk.u;
        }
      }
      // P frags for this s-phase
      f16x8 pa0 = *(const f16x8*)(p_base +
          (((arow) * 128 + sphase * 64 + agrp * 16) ^ ((arow & 7) << 4)));
      f16x8 pa1 = *(const f16x8*)(p_base +
          (((16 + arow) * 128 + sphase * 64 + agrp * 16) ^ ((arow & 7) << 4)));
      __builtin_amdgcn_s_setprio(1);
      #pragma unroll
      for (int n = 0; n < 4; ++n) {
        int hl = n * 16 + arow;
        f16x8 bv = *(const f16x8*)(vt + ((hl * 64 + agrp * 16) ^ (((hl >> 3) & 7) << 4)));
        o_acc[r][0][n] = __builtin_amdgcn_mfma_f32_16x16x32_f16(pa0, bv, o_acc[r][0][n], 0, 0, 0);
        o_acc[r][1][n] = __builtin_amdgcn_mfma_f32_16x16x32_f16(pa1, bv, o_acc[r][1][n], 0, 0, 0);
      }
      __builtin_amdgcn_s_setprio(0);
    }
  }

  // ================= epilogue: O / l =================
  #pragma unroll
  for (int m = 0; m < 2; ++m) {
    #pragma unroll
    for (int i2 = 0; i2 < 4; ++i2) {
      int qr = m * 16 + agrp * 4 + i2;
      float inv = 1.0f / l_lds[qr];
      #pragma unroll
      for (int r = 0; r < 2; ++r)
        #pragma unroll
        for (int n = 0; n < 4; ++n)
          out[((size_t)(b * TQ_ + q0 + qr)) * DH_ + hw * 128 + r * 64 + n * 16 + arow] =
              o_acc[r][m][n][i2] * inv;
    }
  }
}

extern "C" void kernel_launch(void* const* d_in, const int* in_sizes, int n_in,
                              void* d_out, int out_size, void* d_ws, size_t ws_size,
                              hipStream_t stream) {
  (void)in_sizes; (void)n_in; (void)out_size;
  const float* hid = (const float*)d_in[0];
  const float* enc = (const float*)d_in[1];
  float* out = (float*)d_out;

  const size_t encN = (size_t)NB_ * TS_ * DH_;
  const bool ws16 = (ws_size >= encN * sizeof(_Float16));

  dim3 grid(NB_ * (TQ_ / QB_), 1, 1);
  dim3 block(NT_, 1, 1);

  if (ws16) {
    _Float16* encH = (_Float16*)d_ws;
    convert_f32_f16<<<dim3((unsigned)(encN / 8 / 256)), dim3(256), 0, stream>>>(enc, encH);
    attn_v6<true><<<grid, block, 0, stream>>>(hid, enc, encH, out);
  } else {
    attn_v6<false><<<grid, block, 0, stream>>>(hid, enc, nullptr, out);
  }
}

// Round 7
// 1223.650 us; speedup vs baseline: 1.4670x; 1.4016x over previous
//
#include <hip/hip_runtime.h>

#define NB_ 16
#define TQ_ 2048
#define TS_ 2048
#define DH_ 1024
#define QB_ 32
#define SB_ 64
#define NT_ 512

typedef _Float16 f16x8 __attribute__((ext_vector_type(8)));
typedef _Float16 f16x4 __attribute__((ext_vector_type(4)));
typedef float f32x4 __attribute__((ext_vector_type(4)));

// Prologue: enc f32 [b][s][h] -> encH f16 [b][s][h] AND encT f16 [b][h][s]
__global__ void conv_tr(const float* __restrict__ src,
                        _Float16* __restrict__ dH,
                        _Float16* __restrict__ dT) {
  const int b  = blockIdx.x;
  const int st = blockIdx.y;   // s-tile of 64
  const int ht = blockIdx.z;   // h-tile of 64
  const int tid = threadIdx.x;
  __shared__ _Float16 t[64][72];   // +8 pad: transpose-read conflicts ~4-way max

  const size_t base = ((size_t)b * TS_ + (size_t)st * 64) * DH_ + (size_t)ht * 64;
  #pragma unroll
  for (int k = 0; k < 16; ++k) {
    int i = k * 256 + tid;
    int sl = i >> 6, hl = i & 63;
    float v = src[base + (size_t)sl * DH_ + hl];
    _Float16 h = (_Float16)v;
    dH[base + (size_t)sl * DH_ + hl] = h;
    t[sl][hl] = h;
  }
  __syncthreads();
  const size_t tbase = ((size_t)b * DH_ + (size_t)ht * 64) * TS_ + (size_t)st * 64;
  #pragma unroll
  for (int k = 0; k < 8; ++k) {
    int i = k * 256 + tid;          // 2048 u32 units
    int hl = i >> 5, s2 = (i & 31) * 2;
    union { _Float16 h[2]; uint32_t u; } pk;
    pk.h[0] = t[s2][hl];
    pk.h[1] = t[s2 + 1][hl];
    *(uint32_t*)((_Float16*)dT + tbase + (size_t)hl * TS_ + s2) = pk.u;
  }
}

__device__ inline f16x8 cvt8(const float* __restrict__ fp) {
  float4 a = *(const float4*)fp;
  float4 b = *(const float4*)(fp + 4);
  f16x8 t;
  t[0] = (_Float16)a.x; t[1] = (_Float16)a.y; t[2] = (_Float16)a.z; t[3] = (_Float16)a.w;
  t[4] = (_Float16)b.x; t[5] = (_Float16)b.y; t[6] = (_Float16)b.z; t[7] = (_Float16)b.w;
  return t;
}

// LDS layout (bytes), total 41344:
//   s_tiles: 0     .. 36864   8 tiles [(sh*4+dw)][32 q][36] f32
//   p_base : 36864 .. 40960   P [32 q][64 s] f16, byte = (q*128+s*2) ^ ((q&7)<<4)
//   m/l/c  : 40960 .. 41344   softmax state
// VGPR 128 (a_q 64 + staging; o_acc in AGPRs) -> 4 waves/SIMD -> 2 WGs/CU resident.
template<int MODE>   // 1 = encH+encT in ws, 0 = fallback direct f32 (slow, correctness only)
__global__ __launch_bounds__(NT_, 2)
void attn_v7(const float* __restrict__ hid,
             const float* __restrict__ enc,
             const _Float16* __restrict__ encH,
             const _Float16* __restrict__ encT,
             float* __restrict__ out) {
  __shared__ __attribute__((aligned(16))) char smem[41344];
  float* const s_tiles = (float*)smem;
  char*  const p_base  = smem + 36864;
  float* const m_lds   = (float*)(smem + 40960);
  float* const l_lds   = m_lds + 32;
  float* const c_lds   = m_lds + 64;

  const int tid  = threadIdx.x;
  const int lane = tid & 63;
  const int wid  = tid >> 6;
  const int arow = lane & 15;
  const int agrp = lane >> 4;

  // XCD-affine: XCD x sweeps all 64 q-tiles of batch x, then batch x+8.
  const int bi  = blockIdx.x;
  const int x   = bi & 7;
  const int idx = bi >> 3;            // 0..127
  const int b   = x + 8 * (idx >> 6);
  const int q0  = (idx & 63) * QB_;

  const int dw = wid & 3;   // QK^T d-chunk (256 wide)
  const int sh = wid >> 2;  // QK^T s-half (32 wide)
  const int hw = wid;       // PV h-chunk (128 wide)

  if (tid < 32) { m_lds[tid] = -__builtin_inff(); l_lds[tid] = 0.0f; }

  // ---- Q fragments in registers (persistent, 64 VGPR) ----
  f16x8 a_q[2][8];
  #pragma unroll
  for (int m = 0; m < 2; ++m) {
    #pragma unroll
    for (int kf = 0; kf < 8; ++kf) {
      const float* qp = hid + ((size_t)(b * TQ_ + q0 + m * 16 + arow)) * DH_
                            + dw * 256 + kf * 32 + agrp * 8;
      a_q[m][kf] = cvt8(qp);
    }
  }

  f32x4 o_acc[2][8];   // 64 regs persistent (expect AGPR)
  #pragma unroll
  for (int m = 0; m < 2; ++m)
    #pragma unroll
    for (int n = 0; n < 8; ++n)
      o_acc[m][n] = {};

  const size_t enc_b = (size_t)b * TS_ * DH_;   // element base, [s][h] layouts
  const size_t encT_b = (size_t)b * DH_ * TS_;  // element base, [h][s] layout

  for (int st = 0; st < TS_ / SB_; ++st) {
    const int s0 = st * SB_;

    // ================= QK^T: K frags inline from encH (L2-hot) =================
    f32x4 sacc[2][2] = {{{}, {}}, {{}, {}}};
    #pragma unroll
    for (int kf = 0; kf < 8; ++kf) {
      size_t kb = enc_b + (size_t)(s0 + sh * 32 + arow) * DH_ + dw * 256 + kf * 32 + agrp * 8;
      f16x8 bf0, bf1;
      if constexpr (MODE == 1) {
        bf0 = *(const f16x8*)(encH + kb);
        bf1 = *(const f16x8*)(encH + kb + (size_t)16 * DH_);
      } else {
        bf0 = cvt8(enc + kb);
        bf1 = cvt8(enc + kb + (size_t)16 * DH_);
      }
      sacc[0][0] = __builtin_amdgcn_mfma_f32_16x16x32_f16(a_q[0][kf], bf0, sacc[0][0], 0, 0, 0);
      sacc[0][1] = __builtin_amdgcn_mfma_f32_16x16x32_f16(a_q[0][kf], bf1, sacc[0][1], 0, 0, 0);
      sacc[1][0] = __builtin_amdgcn_mfma_f32_16x16x32_f16(a_q[1][kf], bf0, sacc[1][0], 0, 0, 0);
      sacc[1][1] = __builtin_amdgcn_mfma_f32_16x16x32_f16(a_q[1][kf], bf1, sacc[1][1], 0, 0, 0);
    }

    // write partial S tile (sh*4+dw): [32 q][36] f32
    {
      float* tp = s_tiles + (size_t)(sh * 4 + dw) * (32 * 36);
      #pragma unroll
      for (int m = 0; m < 2; ++m)
        #pragma unroll
        for (int n = 0; n < 2; ++n)
          #pragma unroll
          for (int i2 = 0; i2 < 4; ++i2)
            tp[(m * 16 + agrp * 4 + i2) * 36 + n * 16 + arow] = sacc[m][n][i2];
    }

    __syncthreads();  // b1: S complete

    // ---- online softmax over [32 q][64 s] ----
    {
      int q = tid >> 4, sq = tid & 15;
      int shh = sq >> 3, sc = (sq & 7) * 4;
      const float* basep = s_tiles + (size_t)shh * 4 * (32 * 36) + q * 36 + sc;
      f32x4 v = *(const f32x4*)basep;
      v += *(const f32x4*)(basep + 1152);
      v += *(const f32x4*)(basep + 2304);
      v += *(const f32x4*)(basep + 3456);
      float mx = fmaxf(fmaxf(v[0], v[1]), fmaxf(v[2], v[3]));
      #pragma unroll
      for (int o = 8; o; o >>= 1) mx = fmaxf(mx, __shfl_xor(mx, o));
      float mprev = m_lds[q];
      float mnew  = fmaxf(mprev, mx);
      float p0 = __expf(v[0] - mnew), p1 = __expf(v[1] - mnew);
      float p2 = __expf(v[2] - mnew), p3 = __expf(v[3] - mnew);
      float ps = (p0 + p1) + (p2 + p3);
      #pragma unroll
      for (int o = 8; o; o >>= 1) ps += __shfl_xor(ps, o);
      if (sq == 0) {
        float cf = __expf(mprev - mnew);
        m_lds[q] = mnew;
        l_lds[q] = l_lds[q] * cf + ps;
        c_lds[q] = cf;
      }
      f16x4 pw;
      pw[0] = (_Float16)p0; pw[1] = (_Float16)p1;
      pw[2] = (_Float16)p2; pw[3] = (_Float16)p3;
      *(f16x4*)(p_base + ((q * 128 + sq * 8) ^ ((q & 7) << 4))) = pw;
    }

    __syncthreads();  // b2: P + m/l/c complete

    // ---- rescale O ----
    #pragma unroll
    for (int m = 0; m < 2; ++m)
      #pragma unroll
      for (int i2 = 0; i2 < 4; ++i2) {
        float cf = c_lds[m * 16 + agrp * 4 + i2];
        #pragma unroll
        for (int n = 0; n < 8; ++n) o_acc[m][n][i2] *= cf;
      }

    // ================= PV: V B-frags straight from encT (no LDS) =================
    f16x8 pa0  = *(const f16x8*)(p_base + (((arow) * 128 + agrp * 16) ^ ((arow & 7) << 4)));
    f16x8 pa1  = *(const f16x8*)(p_base + (((16 + arow) * 128 + agrp * 16) ^ ((arow & 7) << 4)));
    f16x8 pa0b = *(const f16x8*)(p_base + (((arow) * 128 + 64 + agrp * 16) ^ ((arow & 7) << 4)));
    f16x8 pa1b = *(const f16x8*)(p_base + (((16 + arow) * 128 + 64 + agrp * 16) ^ ((arow & 7) << 4)));

    #pragma unroll
    for (int n = 0; n < 8; ++n) {
      const int hg = hw * 128 + n * 16 + arow;          // global h row of encT
      f16x8 bv0, bv1;
      if constexpr (MODE == 1) {
        const _Float16* vp = encT + encT_b + (size_t)hg * TS_ + s0 + agrp * 8;
        bv0 = *(const f16x8*)vp;          // s = s0 + agrp*8 .. +7
        bv1 = *(const f16x8*)(vp + 32);   // s = s0 + 32 + agrp*8 .. +7
      } else {
        #pragma unroll
        for (int j = 0; j < 8; ++j) {
          bv0[j] = (_Float16)enc[enc_b + (size_t)(s0 + agrp * 8 + j) * DH_ + hg];
          bv1[j] = (_Float16)enc[enc_b + (size_t)(s0 + 32 + agrp * 8 + j) * DH_ + hg];
        }
      }
      o_acc[0][n] = __builtin_amdgcn_mfma_f32_16x16x32_f16(pa0,  bv0, o_acc[0][n], 0, 0, 0);
      o_acc[1][n] = __builtin_amdgcn_mfma_f32_16x16x32_f16(pa1,  bv0, o_acc[1][n], 0, 0, 0);
      o_acc[0][n] = __builtin_amdgcn_mfma_f32_16x16x32_f16(pa0b, bv1, o_acc[0][n], 0, 0, 0);
      o_acc[1][n] = __builtin_amdgcn_mfma_f32_16x16x32_f16(pa1b, bv1, o_acc[1][n], 0, 0, 0);
    }
  }

  // ================= epilogue: O / l =================
  #pragma unroll
  for (int m = 0; m < 2; ++m) {
    #pragma unroll
    for (int i2 = 0; i2 < 4; ++i2) {
      int qr = m * 16 + agrp * 4 + i2;
      float inv = 1.0f / l_lds[qr];
      #pragma unroll
      for (int n = 0; n < 8; ++n) {
        out[((size_t)(b * TQ_ + q0 + qr)) * DH_ + hw * 128 + n * 16 + arow] =
            o_acc[m][n][i2] * inv;
      }
    }
  }
}

extern "C" void kernel_launch(void* const* d_in, const int* in_sizes, int n_in,
                              void* d_out, int out_size, void* d_ws, size_t ws_size,
                              hipStream_t stream) {
  (void)in_sizes; (void)n_in; (void)out_size;
  const float* hid = (const float*)d_in[0];
  const float* enc = (const float*)d_in[1];
  float* out = (float*)d_out;

  const size_t encN = (size_t)NB_ * TS_ * DH_;   // 33554432 elements
  const bool ws_ok = (ws_size >= 2 * encN * sizeof(_Float16));  // encH + encT

  dim3 grid(NB_ * (TQ_ / QB_), 1, 1);
  dim3 block(NT_, 1, 1);

  if (ws_ok) {
    _Float16* encH = (_Float16*)d_ws;
    _Float16* encT = encH + encN;
    dim3 cgrid(NB_, TS_ / 64, DH_ / 64);
    conv_tr<<<cgrid, dim3(256), 0, stream>>>(enc, encH, encT);
    attn_v7<1><<<grid, block, 0, stream>>>(hid, enc, encH, encT, out);
  } else {
    attn_v7<0><<<grid, block, 0, stream>>>(hid, enc, nullptr, nullptr, out);
  }
}

// Round 8
// 851.021 us; speedup vs baseline: 2.1094x; 1.4379x over previous
//
#include <hip/hip_runtime.h>

#define NB_ 16
#define TQ_ 2048
#define TS_ 2048
#define DH_ 1024
#define QB_ 32
#define SB_ 128
#define NT_ 512

typedef _Float16 f16x8 __attribute__((ext_vector_type(8)));
typedef _Float16 f16x4 __attribute__((ext_vector_type(4)));
typedef float f32x4 __attribute__((ext_vector_type(4)));

__device__ inline uint32_t pack_h2(float a, float b) {
  union { _Float16 h[2]; uint32_t u; } c;
  c.h[0] = (_Float16)a; c.h[1] = (_Float16)b;
  return c.u;
}

__global__ void convert_f32_f16(const float* __restrict__ src, _Float16* __restrict__ dst) {
  size_t i = ((size_t)blockIdx.x * blockDim.x + threadIdx.x) * 8;
  float4 v0 = *(const float4*)(src + i);
  float4 v1 = *(const float4*)(src + i + 4);
  f16x8 o;
  o[0] = (_Float16)v0.x; o[1] = (_Float16)v0.y; o[2] = (_Float16)v0.z; o[3] = (_Float16)v0.w;
  o[4] = (_Float16)v1.x; o[5] = (_Float16)v1.y; o[6] = (_Float16)v1.z; o[7] = (_Float16)v1.w;
  *(f16x8*)(dst + i) = o;
}

template<bool WS16>
__device__ inline f16x8 ld8(const _Float16* __restrict__ hp, const float* __restrict__ fp, size_t idx) {
  if constexpr (WS16) {
    return *(const f16x8*)(hp + idx);
  } else {
    float4 a = *(const float4*)(fp + idx);
    float4 b = *(const float4*)(fp + idx + 4);
    f16x8 t;
    t[0] = (_Float16)a.x; t[1] = (_Float16)a.y; t[2] = (_Float16)a.z; t[3] = (_Float16)a.w;
    t[4] = (_Float16)b.x; t[5] = (_Float16)b.y; t[6] = (_Float16)b.z; t[7] = (_Float16)b.w;
    return t;
  }
}

// LDS layout (bytes), total 156544 (<160 KiB, 1 WG/CU):
//   q_base : 0      .. 65536   Q [32 q][1024 d] f16, byte=(q*2048+d*2)^((q&7)<<4)  [v1-verified]
//   s_lds  : 65536  .. 82432   S f32 [32 q][132]  (single-writer full S tile)
//   p_base : 82432  .. 90624   P [32 q][128 s] f16, byte=(q*256+s*2)^((q&7)<<4)
//   vt     : 90624  .. 156160  8 x 8192 per-wave V-transpose [128 h][32 s], v2-verified
//   m/l/c  : 156160 .. 156544  softmax state
template<bool WS16>
__global__ __launch_bounds__(NT_, 2)
void attn_v8(const float* __restrict__ hid,
             const float* __restrict__ enc,
             const _Float16* __restrict__ encH,
             float* __restrict__ out) {
  __shared__ __attribute__((aligned(16))) char smem[156544];
  char*  const q_base = smem;
  float* const s_lds  = (float*)(smem + 65536);
  char*  const p_base = smem + 82432;
  char*  const vt_all = smem + 90624;
  float* const m_lds  = (float*)(smem + 156160);
  float* const l_lds  = m_lds + 32;
  float* const c_lds  = m_lds + 64;

  const int tid  = threadIdx.x;
  const int lane = tid & 63;
  const int wid  = tid >> 6;
  const int arow = lane & 15;
  const int agrp = lane >> 4;

  // XCD-affine: XCD x sweeps all 64 q-tiles of batch x, then batch x+8.
  const int bi  = blockIdx.x;
  const int x   = bi & 7;
  const int idx = bi >> 3;
  const int b   = x + 8 * (idx >> 6);
  const int q0  = (idx & 63) * QB_;

  const int hw = wid;  // PV h-chunk (128 wide); QK^T s-chunk = wid*16

  if (tid < 32) { m_lds[tid] = -__builtin_inff(); l_lds[tid] = 0.0f; }

  // ---- stage Q (32 x 1024) fp32 -> f16 into LDS, swizzled (v1-verified) ----
  {
    const float* qsrc = hid + ((size_t)b * TQ_ + q0) * DH_;
    #pragma unroll
    for (int k = 0; k < 16; ++k) {
      int i = tid + k * NT_;            // 8192 float4 units
      int q = i >> 8;
      int h = (i & 255) * 4;
      float4 v = *(const float4*)(qsrc + (size_t)q * DH_ + h);
      int byte = (q * 2048 + h * 2) ^ ((q & 7) << 4);
      *(uint32_t*)(q_base + byte)     = pack_h2(v.x, v.y);
      *(uint32_t*)(q_base + byte + 4) = pack_h2(v.z, v.w);
    }
  }
  __syncthreads();

  f32x4 o_acc[2][8];   // 64 AGPR persistent
  #pragma unroll
  for (int m = 0; m < 2; ++m)
    #pragma unroll
    for (int n = 0; n < 8; ++n)
      o_acc[m][n] = {};

  char* const vt = vt_all + wid * 8192;
  const size_t enc_b = (size_t)b * TS_ * DH_;
  const int h8  = (lane & 15) * 8;
  const int spb = (lane >> 4) * 2;

  for (int st = 0; st < TS_ / SB_; ++st) {
    const int s0 = st * SB_;

    // ================= QK^T: wave computes full-d S[32q][16s], s-chunk = wid*16 =================
    f32x4 sacc0 = {}, sacc1 = {};
    {
      const size_t krow = enc_b + (size_t)(s0 + wid * 16 + arow) * DH_;
      #pragma unroll
      for (int kf = 0; kf < 32; ++kf) {
        const int d = kf * 32 + agrp * 8;
        f16x8 bf  = ld8<WS16>(encH, enc, krow + d);
        f16x8 af0 = *(const f16x8*)(q_base + ((arow * 2048 + d * 2) ^ ((arow & 7) << 4)));
        f16x8 af1 = *(const f16x8*)(q_base + (((16 + arow) * 2048 + d * 2) ^ ((arow & 7) << 4)));
        sacc0 = __builtin_amdgcn_mfma_f32_16x16x32_f16(af0, bf, sacc0, 0, 0, 0);
        sacc1 = __builtin_amdgcn_mfma_f32_16x16x32_f16(af1, bf, sacc1, 0, 0, 0);
      }
    }

    // ---- issue PV phase-0 V loads early (hide under S-write + softmax + barriers) ----
    f16x8 stg[4][2];
    #pragma unroll
    for (int it = 0; it < 4; ++it) {
      size_t base = enc_b + (size_t)(s0 + it * 8 + spb) * DH_ + hw * 128 + h8;
      stg[it][0] = ld8<WS16>(encH, enc, base);
      stg[it][1] = ld8<WS16>(encH, enc, base + DH_);
    }

    // write S tile (single writer per element): row=q, col = wid*16 + arow
    {
      const int sc = wid * 16 + arow;
      #pragma unroll
      for (int i2 = 0; i2 < 4; ++i2) {
        s_lds[(agrp * 4 + i2) * 132 + sc]        = sacc0[i2];
        s_lds[(16 + agrp * 4 + i2) * 132 + sc]   = sacc1[i2];
      }
    }

    __syncthreads();  // b1: S complete

    // ================= online softmax over [32 q][128 s] =================
    {
      int q = tid >> 4, sq = tid & 15;   // 16 threads/row, 8 s each (sq*4 and 64+sq*4)
      const float* bp = s_lds + q * 132 + sq * 4;
      f32x4 va = *(const f32x4*)bp;
      f32x4 vb = *(const f32x4*)(bp + 64);
      float mx = fmaxf(fmaxf(fmaxf(va[0], va[1]), fmaxf(va[2], va[3])),
                       fmaxf(fmaxf(vb[0], vb[1]), fmaxf(vb[2], vb[3])));
      #pragma unroll
      for (int o = 8; o; o >>= 1) mx = fmaxf(mx, __shfl_xor(mx, o));
      float mprev = m_lds[q];
      float mnew  = fmaxf(mprev, mx);
      float pa0 = __expf(va[0] - mnew), pa1 = __expf(va[1] - mnew);
      float pa2 = __expf(va[2] - mnew), pa3 = __expf(va[3] - mnew);
      float pb0 = __expf(vb[0] - mnew), pb1 = __expf(vb[1] - mnew);
      float pb2 = __expf(vb[2] - mnew), pb3 = __expf(vb[3] - mnew);
      float ps = ((pa0 + pa1) + (pa2 + pa3)) + ((pb0 + pb1) + (pb2 + pb3));
      #pragma unroll
      for (int o = 8; o; o >>= 1) ps += __shfl_xor(ps, o);
      if (sq == 0) {
        float cf = __expf(mprev - mnew);
        m_lds[q] = mnew;
        l_lds[q] = l_lds[q] * cf + ps;
        c_lds[q] = cf;
      }
      f16x4 pwa, pwb;
      pwa[0] = (_Float16)pa0; pwa[1] = (_Float16)pa1;
      pwa[2] = (_Float16)pa2; pwa[3] = (_Float16)pa3;
      pwb[0] = (_Float16)pb0; pwb[1] = (_Float16)pb1;
      pwb[2] = (_Float16)pb2; pwb[3] = (_Float16)pb3;
      *(f16x4*)(p_base + ((q * 256 + sq * 8) ^ ((q & 7) << 4)))       = pwa;
      *(f16x4*)(p_base + ((q * 256 + 128 + sq * 8) ^ ((q & 7) << 4))) = pwb;
    }

    __syncthreads();  // b2: P + m/l/c complete

    // ---- rescale O ----
    #pragma unroll
    for (int m = 0; m < 2; ++m)
      #pragma unroll
      for (int i2 = 0; i2 < 4; ++i2) {
        float cf = c_lds[m * 16 + agrp * 4 + i2];
        #pragma unroll
        for (int n = 0; n < 8; ++n) o_acc[m][n][i2] *= cf;
      }

    // ================= PV: 4 phases of 32 s (v2-verified vt structure) =================
    #pragma unroll
    for (int ph = 0; ph < 4; ++ph) {
      // write Vt (wave-private, DS in-order, no barrier)
      #pragma unroll
      for (int it = 0; it < 4; ++it) {
        int sp = it * 8 + spb;
        #pragma unroll
        for (int jj = 0; jj < 8; ++jj) {
          int hloc = h8 + jj;
          union { _Float16 h[2]; uint32_t u; } pk;
          pk.h[0] = stg[it][0][jj]; pk.h[1] = stg[it][1][jj];
          *(uint32_t*)(vt + ((hloc * 64 + sp * 2) ^ (((hloc >> 3) & 7) << 4))) = pk.u;
        }
      }
      // issue next phase's V loads (overlap with MFMAs below)
      if (ph < 3) {
        #pragma unroll
        for (int it = 0; it < 4; ++it) {
          size_t base = enc_b + (size_t)(s0 + (ph + 1) * 32 + it * 8 + spb) * DH_ + hw * 128 + h8;
          stg[it][0] = ld8<WS16>(encH, enc, base);
          stg[it][1] = ld8<WS16>(encH, enc, base + DH_);
        }
      }
      // P A-frags for this phase (k = ph*32 + agrp*8 + j)
      f16x8 paf0 = *(const f16x8*)(p_base +
          ((arow * 256 + ph * 64 + agrp * 16) ^ ((arow & 7) << 4)));
      f16x8 paf1 = *(const f16x8*)(p_base +
          (((16 + arow) * 256 + ph * 64 + agrp * 16) ^ ((arow & 7) << 4)));
      __builtin_amdgcn_s_setprio(1);
      #pragma unroll
      for (int n = 0; n < 8; ++n) {
        int hloc = n * 16 + arow;
        f16x8 bv = *(const f16x8*)(vt + ((hloc * 64 + agrp * 16) ^ (((hloc >> 3) & 7) << 4)));
        o_acc[0][n] = __builtin_amdgcn_mfma_f32_16x16x32_f16(paf0, bv, o_acc[0][n], 0, 0, 0);
        o_acc[1][n] = __builtin_amdgcn_mfma_f32_16x16x32_f16(paf1, bv, o_acc[1][n], 0, 0, 0);
      }
      __builtin_amdgcn_s_setprio(0);
    }
  }

  // ================= epilogue: O / l =================
  #pragma unroll
  for (int m = 0; m < 2; ++m) {
    #pragma unroll
    for (int i2 = 0; i2 < 4; ++i2) {
      int qr = m * 16 + agrp * 4 + i2;
      float inv = 1.0f / l_lds[qr];
      #pragma unroll
      for (int n = 0; n < 8; ++n) {
        out[((size_t)(b * TQ_ + q0 + qr)) * DH_ + hw * 128 + n * 16 + arow] =
            o_acc[m][n][i2] * inv;
      }
    }
  }
}

extern "C" void kernel_launch(void* const* d_in, const int* in_sizes, int n_in,
                              void* d_out, int out_size, void* d_ws, size_t ws_size,
                              hipStream_t stream) {
  (void)in_sizes; (void)n_in; (void)out_size;
  const float* hid = (const float*)d_in[0];
  const float* enc = (const float*)d_in[1];
  float* out = (float*)d_out;

  const size_t encN = (size_t)NB_ * TS_ * DH_;
  const bool ws16 = (ws_size >= encN * sizeof(_Float16));

  dim3 grid(NB_ * (TQ_ / QB_), 1, 1);
  dim3 block(NT_, 1, 1);

  if (ws16) {
    _Float16* encH = (_Float16*)d_ws;
    convert_f32_f16<<<dim3((unsigned)(encN / 8 / 256)), dim3(256), 0, stream>>>(enc, encH);
    attn_v8<true><<<grid, block, 0, stream>>>(hid, enc, encH, out);
  } else {
    attn_v8<false><<<grid, block, 0, stream>>>(hid, enc, nullptr, out);
  }
}